// Round 2
// baseline (2204.136 us; speedup 1.0000x reference)
//
#include <hip/hip_runtime.h>
#include <math.h>

#define Bn 4
#define Cn 7
#define Hn 512
#define Wn 1024
#define HWn (Hn*Wn)
#define NID 7
#define NPAIR (Bn*NID)
#define NB 16385   // float bits >> 16, e in [0,2] -> 0..16384

// ---------------- static device state (re-zeroed every launch) ----------------
__device__ double   g_stats[NPAIR][7];   // cnt, Sxm, Sym, Ss0, Ss1, Ss0^2, Ss1^2
__device__ double   g_cls[Bn][2];        // focal_sum, valid_cnt
__device__ double   g_seedbg[Bn];
__device__ double   g_seedfg[NPAIR];     // sum (seed-dist)^2 over mask
__device__ unsigned g_top1[NPAIR];       // label-1 elements with e == 2.0f exactly
__device__ float    g_center[NPAIR][2];
__device__ float    g_sexp[NPAIR][2];
__device__ float    g_var[NPAIR];
__device__ float    g_cnt[NPAIR];
__device__ float    g_instl[NPAIR];
__device__ unsigned g_h_cnt[NPAIR][2][NB];
__device__ float    g_h_sum[NPAIR][2][NB];

// ---------------- helpers ----------------
__device__ inline unsigned exscan64_u32(unsigned v) {
    int lane = threadIdx.x & 63;
    unsigned x = v;
#pragma unroll
    for (int d = 1; d < 64; d <<= 1) {
        unsigned y = __shfl_up(x, d, 64);
        if (lane >= d) x += y;
    }
    return x - v;
}

__device__ inline double wavesum_f64(double v) {
#pragma unroll
    for (int d = 32; d > 0; d >>= 1) v += __shfl_down(v, d, 64);
    return v;  // valid on lane 0
}

// ---------------- kernels ----------------
__global__ void k_zero() {
    size_t n = (size_t)NPAIR * 2 * NB;
    size_t stride = (size_t)gridDim.x * blockDim.x;
    for (size_t i = (size_t)blockIdx.x * blockDim.x + threadIdx.x; i < n; i += stride) {
        ((unsigned*)g_h_cnt)[i] = 0u;
        ((float*)g_h_sum)[i] = 0.f;
    }
    if (blockIdx.x == 0 && threadIdx.x < NPAIR) {
        int p = threadIdx.x;
        for (int s = 0; s < 7; ++s) g_stats[p][s] = 0.0;
        g_seedfg[p] = 0.0;
        g_top1[p] = 0u;
        if (p < Bn) { g_cls[p][0] = 0.0; g_cls[p][1] = 0.0; g_seedbg[p] = 0.0; }
    }
}

__global__ __launch_bounds__(256) void k_stats(const float* __restrict__ pred,
                                               const int* __restrict__ inst,
                                               const int* __restrict__ lab) {
    int b = blockIdx.y;
    int pix = blockIdx.x * blockDim.x + threadIdx.x;
    __shared__ float ls[NID][7];
    __shared__ float lcls[3];   // focal, validcnt, seedbg
    if (threadIdx.x < NID * 7) ((float*)ls)[threadIdx.x] = 0.f;
    if (threadIdx.x >= 56 && threadIdx.x < 59) lcls[threadIdx.x - 56] = 0.f;
    __syncthreads();

    if (pix < HWn) {
        int y = pix >> 10;          // W = 1024
        int x = pix & 1023;
        float xm = (float)x * (2.0f / 2047.0f);
        float ym = (float)y * (1.0f / 1023.0f);
        const float* pb = pred + (size_t)b * Cn * HWn;
        int   iv = inst[(size_t)b * HWn + pix];
        int   lv = lab [(size_t)b * HWn + pix];
        float s0 = pb[2 * (size_t)HWn + pix];
        float s1 = pb[3 * (size_t)HWn + pix];
        if (iv >= 1) {
            int id = iv - 1;
            atomicAdd(&ls[id][0], 1.f);
            atomicAdd(&ls[id][1], xm);
            atomicAdd(&ls[id][2], ym);
            atomicAdd(&ls[id][3], s0);
            atomicAdd(&ls[id][4], s1);
            atomicAdd(&ls[id][5], s0 * s0);
            atomicAdd(&ls[id][6], s1 * s1);
        }
        float c0 = pb[5 * (size_t)HWn + pix];
        float c1 = pb[6 * (size_t)HWn + pix];
        if (lv < 2) {
            float m = fmaxf(c0, c1);
            float lse = m + logf(expf(c0 - m) + expf(c1 - m));
            float logpt = (lv == 0 ? c0 : c1) - lse;
            float pt = expf(logpt);
            float om = 1.f - pt;
            atomicAdd(&lcls[0], -om * om * logpt);
            atomicAdd(&lcls[1], 1.f);
        }
        if (lv == 0) {
            float p4 = pb[4 * (size_t)HWn + pix];
            float seed = 1.f / (1.f + expf(-p4));
            atomicAdd(&lcls[2], seed * seed);
        }
    }
    __syncthreads();
    if (threadIdx.x < NID * 7) {
        int id = threadIdx.x / 7, s = threadIdx.x % 7;
        float v = ls[id][s];
        if (v != 0.f) atomicAdd(&g_stats[b * NID + id][s], (double)v);
    } else if (threadIdx.x == 56) {
        if (lcls[0] != 0.f) atomicAdd(&g_cls[b][0], (double)lcls[0]);
    } else if (threadIdx.x == 57) {
        if (lcls[1] != 0.f) atomicAdd(&g_cls[b][1], (double)lcls[1]);
    } else if (threadIdx.x == 58) {
        if (lcls[2] != 0.f) atomicAdd(&g_seedbg[b], (double)lcls[2]);
    }
}

__global__ void k_finalize() {
    int p = threadIdx.x;
    if (p >= NPAIR) return;
    double cnt  = g_stats[p][0];
    double cntf = fmax(cnt, 1.0);
    g_cnt[p] = (float)cnt;
    float cx = (float)(g_stats[p][1] / cntf);
    float cy = (float)(g_stats[p][2] / cntf);
    double m0 = g_stats[p][3] / cntf;
    double m1 = g_stats[p][4] / cntf;
    g_center[p][0] = cx;
    g_center[p][1] = cy;
    g_sexp[p][0] = expf(10.f * (float)m0);
    g_sexp[p][1] = expf(10.f * (float)m1);
    double varsum = (g_stats[p][5] - cnt * m0 * m0) + (g_stats[p][6] - cnt * m1 * m1);
    g_var[p] = (float)(varsum / (2.0 * cntf));
}

__global__ __launch_bounds__(256) void k_hist(const float* __restrict__ pred,
                                              const int* __restrict__ inst) {
    int b = blockIdx.y;
    __shared__ float sc[NID][4];      // cx, cy, sx, sy
    __shared__ float lseed[NID];
    __shared__ unsigned ltop[NID];
    if (threadIdx.x < NID) {
        int p = b * NID + threadIdx.x;
        sc[threadIdx.x][0] = g_center[p][0];
        sc[threadIdx.x][1] = g_center[p][1];
        sc[threadIdx.x][2] = g_sexp[p][0];
        sc[threadIdx.x][3] = g_sexp[p][1];
        lseed[threadIdx.x] = 0.f;
        ltop[threadIdx.x] = 0u;
    }
    __syncthreads();

    int pix = blockIdx.x * blockDim.x + threadIdx.x;
    if (pix < HWn) {
        int y = pix >> 10;
        int x = pix & 1023;
        float xm = (float)x * (2.0f / 2047.0f);
        float ym = (float)y * (1.0f / 1023.0f);
        const float* pb = pred + (size_t)b * Cn * HWn;
        float p0 = pb[0 * (size_t)HWn + pix];
        float p1 = pb[1 * (size_t)HWn + pix];
        float p4 = pb[4 * (size_t)HWn + pix];
        int   iv = inst[(size_t)b * HWn + pix];
        float ex = tanhf(p0) + xm;
        float ey = tanhf(p1) + ym;
        float seed = 1.f / (1.f + expf(-p4));
#pragma unroll
        for (int v = 1; v <= NID; ++v) {
            int id = v - 1;
            int pair = b * NID + id;
            float dx = ex - sc[id][0];
            float dy = ey - sc[id][1];
            float dist = expf(-(dx * dx * sc[id][2] + dy * dy * sc[id][3]));
            bool gt = (iv == v);
            float sgn = gt ? 1.f : -1.f;
            float e = 1.f - (2.f * dist - 1.f) * sgn;
            if (gt) {
                float d2 = seed - dist;
                atomicAdd(&lseed[id], d2 * d2);
                if (e == 2.0f) {
                    atomicAdd(&ltop[id], 1u);
                } else {
                    unsigned k = __float_as_uint(e) >> 16;
                    atomicAdd(&g_h_cnt[pair][1][k], 1u);
                    atomicAdd(&g_h_sum[pair][1][k], e);
                }
            } else if (e > 1e-12f) {
                unsigned k = __float_as_uint(e) >> 16;
                atomicAdd(&g_h_cnt[pair][0][k], 1u);
                atomicAdd(&g_h_sum[pair][0][k], e);
            }
        }
    }
    __syncthreads();
    if (threadIdx.x < NID) {
        if (lseed[threadIdx.x] != 0.f) atomicAdd(&g_seedfg[b * NID + threadIdx.x], (double)lseed[threadIdx.x]);
        if (ltop[threadIdx.x]) atomicAdd(&g_top1[b * NID + threadIdx.x], ltop[threadIdx.x]);
    }
}

// one wave per (b,id) pair: descending-order scan over buckets
__global__ __launch_bounds__(64) void k_scan() {
    int pair = blockIdx.x;
    int lane = threadIdx.x;
    float G = g_cnt[pair];
    if (G <= 0.f) { if (lane == 0) g_instl[pair] = 0.f; return; }
    const int CH = (NB + 63) / 64;      // 257
    int j0 = lane * CH;
    int j1 = min(j0 + CH, NB);
    unsigned c0 = 0, c1 = 0;
    for (int j = j0; j < j1; ++j) {
        int k = NB - 1 - j;
        c0 += g_h_cnt[pair][0][k];
        c1 += g_h_cnt[pair][1][k];
    }
    unsigned r0  = exscan64_u32(c0);
    unsigned s10 = exscan64_u32(c1);
    float top = (float)g_top1[pair];
    double acc = 0.0;
    float r = (float)r0;
    float S = top + (float)s10;
    for (int j = j0; j < j1; ++j) {
        int k = NB - 1 - j;
        unsigned cc1 = g_h_cnt[pair][1][k];
        unsigned cc0 = g_h_cnt[pair][0][k];
        float Sin = S + (float)cc1;
        if (cc1) acc += (double)g_h_sum[pair][1][k] / (double)(G + r);
        if (cc0) {
            double gr = (double)(G + r);
            acc += ((double)g_h_sum[pair][0][k] / (double)cc0)
                 * (double)(G - Sin)
                 * (1.0 / gr - 1.0 / (gr + (double)cc0));
        }
        r += (float)cc0;
        S = Sin;
    }
    acc = wavesum_f64(acc);
    if (lane == 0)
        g_instl[pair] = (float)(acc + (top > 0.f ? 2.0 * (double)top / (double)G : 0.0));
}

__global__ void k_final(float* __restrict__ out) {
    if (blockIdx.x != 0 || threadIdx.x != 0) return;
    double tot = 0.0, totc = 0.0;
    for (int b = 0; b < Bn; ++b) {
        double pres = 0.0, il = 0.0, vl = 0.0, sf = 0.0;
        for (int id = 0; id < NID; ++id) {
            int p = b * NID + id;
            if (g_cnt[p] > 0.f) {
                pres += 1.0;
                il += (double)g_instl[p];
                vl += (double)g_var[p];
                sf += 200.0 * g_seedfg[p];
            }
        }
        double obj = fmax(pres, 1.0);
        double seed_loss = (g_seedbg[b] + sf) / (double)HWn;
        double loss_b = il / obj + 10.0 * vl / obj + seed_loss;
        tot += loss_b;
        double vc = fmax(g_cls[b][1], 1.0);
        totc += g_cls[b][0] / vc;
    }
    out[0] = (float)(tot / (double)Bn + totc / (double)Bn);
}

// ---------------- launch ----------------
extern "C" void kernel_launch(void* const* d_in, const int* in_sizes, int n_in,
                              void* d_out, int out_size, void* d_ws, size_t ws_size,
                              hipStream_t stream) {
    const float* pred = (const float*)d_in[0];
    const int*   inst = (const int*)d_in[1];
    const int*   lab  = (const int*)d_in[2];
    float* out = (float*)d_out;

    k_zero<<<512, 256, 0, stream>>>();
    dim3 grid((HWn + 255) / 256, Bn);
    k_stats<<<grid, 256, 0, stream>>>(pred, inst, lab);
    k_finalize<<<1, 32, 0, stream>>>();
    k_hist<<<grid, 256, 0, stream>>>(pred, inst);
    k_scan<<<NPAIR, 64, 0, stream>>>();
    k_final<<<1, 1, 0, stream>>>(out);
}

// Round 3
// 317.388 us; speedup vs baseline: 6.9446x; 6.9446x over previous
//
#include <hip/hip_runtime.h>
#include <math.h>

#define Bn 4
#define Cn 7
#define HWn (512*1024)
#define NID 7
#define NPAIR 28
#define NBK 256          // linear buckets over e in [0,2], width 1/128
#define PX 16            // pixels per thread
#define NCHUNK 128       // HWn / (256*PX)
#define SLICE (NID*2*NBK)   // 3584 floats per (b,chunk) slice

// ---------------- static device state ----------------
__device__ double   g_stats[NPAIR][7];   // cnt, Sxm, Sym, Ss0, Ss1, Ss0^2, Ss1^2
__device__ double   g_cls[Bn][2];        // focal_sum, valid_cnt
__device__ double   g_seedbg[Bn];
__device__ double   g_seedfg[NPAIR];
__device__ unsigned g_top1[NPAIR];       // label-1 elements with e == 2.0f exactly
__device__ float    g_instl[NPAIR];
__device__ float    g_pcnt[Bn*NCHUNK*SLICE];   // per-block histogram slices (no atomics)
__device__ float    g_psum[Bn*NCHUNK*SLICE];

// ---------------- helpers ----------------
__device__ inline float wavesum_f32(float v) {
#pragma unroll
    for (int d = 32; d > 0; d >>= 1) v += __shfl_xor(v, d, 64);
    return v;
}
__device__ inline double wavesum_f64(double v) {
#pragma unroll
    for (int d = 32; d > 0; d >>= 1) v += __shfl_down(v, d, 64);
    return v;  // lane 0
}
__device__ inline float exscan64_f32(float v, int lane) {
    float x = v;
#pragma unroll
    for (int d = 1; d < 64; d <<= 1) {
        float y = __shfl_up(x, d, 64);
        if (lane >= d) x += y;
    }
    return x - v;
}

// ---------------- kernels ----------------
__global__ void k_zero() {
    int t = threadIdx.x;
    double* sp = (double*)g_stats;                 // 196 doubles
    for (int i = t; i < NPAIR * 7; i += 256) sp[i] = 0.0;
    if (t < Bn * 2) ((double*)g_cls)[t] = 0.0;
    if (t < Bn) g_seedbg[t] = 0.0;
    if (t < NPAIR) { g_seedfg[t] = 0.0; g_top1[t] = 0u; }
}

__global__ __launch_bounds__(256) void k_stats(const float* __restrict__ pred,
                                               const int* __restrict__ inst,
                                               const int* __restrict__ lab) {
    int b = blockIdx.y;
    int t = threadIdx.x;
    int lane = t & 63;
    float acc[NID * 7];
#pragma unroll
    for (int i = 0; i < NID * 7; ++i) acc[i] = 0.f;
    float fa = 0.f, va = 0.f, sb = 0.f;

    const float* pb = pred + (size_t)b * Cn * HWn;
    const int*   ib = inst + (size_t)b * HWn;
    const int*   lb = lab  + (size_t)b * HWn;
    int pix0 = blockIdx.x * (256 * PX) + t;

#pragma unroll 2
    for (int i = 0; i < PX; ++i) {
        int pix = pix0 + i * 256;
        int y = pix >> 10;
        int x = pix & 1023;
        float xm = (float)x * (2.0f / 2047.0f);
        float ym = (float)y * (1.0f / 1023.0f);
        int iv = ib[pix];
        int lv = lb[pix];
        float s0 = pb[2 * (size_t)HWn + pix];
        float s1 = pb[3 * (size_t)HWn + pix];
#pragma unroll
        for (int id = 0; id < NID; ++id) {
            float m = (iv == id + 1) ? 1.f : 0.f;
            int a = id * 7;
            acc[a + 0] += m;
            acc[a + 1] += m * xm;
            acc[a + 2] += m * ym;
            acc[a + 3] += m * s0;
            acc[a + 4] += m * s1;
            acc[a + 5] += m * s0 * s0;
            acc[a + 6] += m * s1 * s1;
        }
        if (lv < 2) {
            float c0 = pb[5 * (size_t)HWn + pix];
            float c1 = pb[6 * (size_t)HWn + pix];
            float mx = fmaxf(c0, c1);
            float lse = mx + logf(expf(c0 - mx) + expf(c1 - mx));
            float logpt = (lv == 0 ? c0 : c1) - lse;
            float pt = expf(logpt);
            float om = 1.f - pt;
            fa += -om * om * logpt;
            va += 1.f;
        }
        if (lv == 0) {
            float p4 = pb[4 * (size_t)HWn + pix];
            float seed = 1.f / (1.f + expf(-p4));
            sb += seed * seed;
        }
    }

    __shared__ float ls[NID * 7 + 3];
    if (t < NID * 7 + 3) ls[t] = 0.f;
    __syncthreads();
#pragma unroll
    for (int i = 0; i < NID * 7; ++i) {
        float v = wavesum_f32(acc[i]);
        if (lane == 0 && v != 0.f) atomicAdd(&ls[i], v);
    }
    {
        float v = wavesum_f32(fa);
        if (lane == 0 && v != 0.f) atomicAdd(&ls[NID * 7 + 0], v);
        v = wavesum_f32(va);
        if (lane == 0 && v != 0.f) atomicAdd(&ls[NID * 7 + 1], v);
        v = wavesum_f32(sb);
        if (lane == 0 && v != 0.f) atomicAdd(&ls[NID * 7 + 2], v);
    }
    __syncthreads();
    if (t < NID * 7) {
        int id = t / 7, s = t % 7;
        if (ls[t] != 0.f) atomicAdd(&g_stats[b * NID + id][s], (double)ls[t]);
    } else if (t == NID * 7 + 0) {
        if (ls[t] != 0.f) atomicAdd(&g_cls[b][0], (double)ls[t]);
    } else if (t == NID * 7 + 1) {
        if (ls[t] != 0.f) atomicAdd(&g_cls[b][1], (double)ls[t]);
    } else if (t == NID * 7 + 2) {
        if (ls[t] != 0.f) atomicAdd(&g_seedbg[b], (double)ls[t]);
    }
}

__global__ __launch_bounds__(256) void k_hist(const float* __restrict__ pred,
                                              const int* __restrict__ inst) {
    int b = blockIdx.y;
    int chunk = blockIdx.x;
    int t = threadIdx.x;

    __shared__ float hcnt[SLICE];    // [id][cls][k]
    __shared__ float hsum[SLICE];
    __shared__ float sc[NID][4];     // cx, cy, sx, sy
    __shared__ float lseed[NID];
    __shared__ unsigned ltop[NID];

    for (int i = t; i < SLICE; i += 256) { hcnt[i] = 0.f; hsum[i] = 0.f; }
    if (t < NID) {
        int p = b * NID + t;
        double cnt  = g_stats[p][0];
        double cntf = fmax(cnt, 1.0);
        sc[t][0] = (float)(g_stats[p][1] / cntf);
        sc[t][1] = (float)(g_stats[p][2] / cntf);
        sc[t][2] = expf(10.f * (float)(g_stats[p][3] / cntf));
        sc[t][3] = expf(10.f * (float)(g_stats[p][4] / cntf));
        lseed[t] = 0.f;
        ltop[t] = 0u;
    }
    __syncthreads();

    const float* pb = pred + (size_t)b * Cn * HWn;
    const int*   ib = inst + (size_t)b * HWn;
    int pix0 = chunk * (256 * PX) + t;

    for (int i = 0; i < PX; ++i) {
        int pix = pix0 + i * 256;
        int y = pix >> 10;
        int x = pix & 1023;
        float xm = (float)x * (2.0f / 2047.0f);
        float ym = (float)y * (1.0f / 1023.0f);
        float p0 = pb[0 * (size_t)HWn + pix];
        float p1 = pb[1 * (size_t)HWn + pix];
        float p4 = pb[4 * (size_t)HWn + pix];
        int   iv = ib[pix];
        float ex = tanhf(p0) + xm;
        float ey = tanhf(p1) + ym;
        float seed = 1.f / (1.f + expf(-p4));
#pragma unroll
        for (int id = 0; id < NID; ++id) {
            float dx = ex - sc[id][0];
            float dy = ey - sc[id][1];
            float tt = dx * dx * sc[id][2] + dy * dy * sc[id][3];
            float dist = __expf(-tt);
            bool gt = (iv == id + 1);
            if (gt) {
                float e = 2.f - 2.f * dist;
                float d2 = seed - dist;
                atomicAdd(&lseed[id], d2 * d2);
                if (e == 2.0f) {
                    atomicAdd(&ltop[id], 1u);
                } else {
                    int k = min(NBK - 1, (int)(e * 128.f));
                    atomicAdd(&hcnt[(id * 2 + 1) * NBK + k], 1.f);
                    atomicAdd(&hsum[(id * 2 + 1) * NBK + k], e);
                }
            } else {
                float e = 2.f * dist;
                if (e > 1e-12f) {
                    int k = min(NBK - 1, (int)(e * 128.f));
                    atomicAdd(&hcnt[(id * 2 + 0) * NBK + k], 1.f);
                    atomicAdd(&hsum[(id * 2 + 0) * NBK + k], e);
                }
            }
        }
    }
    __syncthreads();

    size_t base = ((size_t)b * NCHUNK + chunk) * SLICE;
    for (int i = t; i < SLICE; i += 256) {
        g_pcnt[base + i] = hcnt[i];
        g_psum[base + i] = hsum[i];
    }
    if (t < NID) {
        if (lseed[t] != 0.f) atomicAdd(&g_seedfg[b * NID + t], (double)lseed[t]);
        if (ltop[t]) atomicAdd(&g_top1[b * NID + t], ltop[t]);
    }
}

// grid = 28 pairs, 512 threads: wave-coalesced partial reduction + descending scan
__global__ __launch_bounds__(512) void k_scan() {
    int pair = blockIdx.x;
    int b = pair / NID, id = pair % NID;
    int t = threadIdx.x;

    __shared__ float  scnt[2 * NBK];
    __shared__ double ssum[2 * NBK];

    // entry t = cls*NBK + k ; sum over the NCHUNK slices (coalesced in t)
    float  cacc = 0.f;
    double sacc = 0.0;
#pragma unroll 4
    for (int c = 0; c < NCHUNK; ++c) {
        size_t off = ((size_t)b * NCHUNK + c) * SLICE + (size_t)id * (2 * NBK) + t;
        cacc += g_pcnt[off];
        sacc += (double)g_psum[off];
    }
    scnt[t] = cacc;
    ssum[t] = sacc;
    __syncthreads();

    if (t < 64) {
        int lane = t;
        double G = g_stats[pair][0];
        if (G <= 0.0) {
            if (lane == 0) g_instl[pair] = 0.f;
            return;
        }
        // lane handles 4 buckets in descending-e order: j = lane*4+jj, k = NBK-1-j
        float c0 = 0.f, c1 = 0.f;
#pragma unroll
        for (int jj = 0; jj < 4; ++jj) {
            int k = NBK - 1 - (lane * 4 + jj);
            c0 += scnt[k];
            c1 += scnt[NBK + k];
        }
        float r0  = exscan64_f32(c0, lane);
        float s1b = exscan64_f32(c1, lane);
        float top = (float)g_top1[pair];
        double acc = 0.0;
        double r = (double)r0;
        double S = (double)top + (double)s1b;
#pragma unroll
        for (int jj = 0; jj < 4; ++jj) {
            int k = NBK - 1 - (lane * 4 + jj);
            double cc1 = (double)scnt[NBK + k];
            double cc0 = (double)scnt[k];
            double Sin = S + cc1;
            if (cc1 > 0.0) acc += ssum[NBK + k] / (G + r);
            if (cc0 > 0.0) {
                double gr = G + r;
                acc += (ssum[k] / cc0) * (G - Sin) * (1.0 / gr - 1.0 / (gr + cc0));
            }
            r += cc0;
            S = Sin;
        }
        acc = wavesum_f64(acc);
        if (lane == 0)
            g_instl[pair] = (float)(acc + (top > 0.f ? 2.0 * (double)top / G : 0.0));
    }
}

__global__ void k_final(float* __restrict__ out) {
    if (blockIdx.x != 0 || threadIdx.x != 0) return;
    double tot = 0.0, totc = 0.0;
    for (int b = 0; b < Bn; ++b) {
        double pres = 0.0, il = 0.0, vl = 0.0, sf = 0.0;
        for (int id = 0; id < NID; ++id) {
            int p = b * NID + id;
            double cnt = g_stats[p][0];
            if (cnt > 0.0) {
                pres += 1.0;
                il += (double)g_instl[p];
                double m0 = g_stats[p][3] / cnt;
                double m1 = g_stats[p][4] / cnt;
                double varsum = (g_stats[p][5] - cnt * m0 * m0) + (g_stats[p][6] - cnt * m1 * m1);
                vl += varsum / (2.0 * cnt);
                sf += 200.0 * g_seedfg[p];
            }
        }
        double obj = fmax(pres, 1.0);
        double seed_loss = (g_seedbg[b] + sf) / (double)HWn;
        tot += il / obj + 10.0 * vl / obj + seed_loss;
        double vc = fmax(g_cls[b][1], 1.0);
        totc += g_cls[b][0] / vc;
    }
    out[0] = (float)(tot / (double)Bn + totc / (double)Bn);
}

// ---------------- launch ----------------
extern "C" void kernel_launch(void* const* d_in, const int* in_sizes, int n_in,
                              void* d_out, int out_size, void* d_ws, size_t ws_size,
                              hipStream_t stream) {
    const float* pred = (const float*)d_in[0];
    const int*   inst = (const int*)d_in[1];
    const int*   lab  = (const int*)d_in[2];
    float* out = (float*)d_out;

    k_zero<<<1, 256, 0, stream>>>();
    dim3 grid(NCHUNK, Bn);
    k_stats<<<grid, 256, 0, stream>>>(pred, inst, lab);
    k_hist<<<grid, 256, 0, stream>>>(pred, inst);
    k_scan<<<NPAIR, 512, 0, stream>>>();
    k_final<<<1, 1, 0, stream>>>(out);
}

// Round 4
// 214.900 us; speedup vs baseline: 10.2566x; 1.4769x over previous
//
#include <hip/hip_runtime.h>
#include <math.h>

#define Bn 4
#define Cn 7
#define HWn (512*1024)
#define NID 7
#define NPAIR 28
#define NBK 256               // linear buckets over e in [0,2], width 1/128
#define PXS 4                 // pixels/thread in k_stats
#define NCH_S (HWn/(256*PXS)) // 512
#define PXH 8                 // pixels/thread in k_hist
#define NCH_H (HWn/(256*PXH)) // 256
#define SLICE (NID*2*NBK)     // 3584 u32 per (b,chunk) slice

// ---------------- static device state ----------------
__device__ double   g_stats[NPAIR][7];   // cnt, Sxm, Sym, Ss0, Ss1, Ss0^2, Ss1^2
__device__ double   g_cls[Bn][2];        // focal_sum, valid_cnt
__device__ double   g_seedbg[Bn];
__device__ double   g_seedfg[NPAIR];
__device__ float    g_instl[NPAIR];
__device__ unsigned g_pcnt[(size_t)Bn*NCH_H*SLICE];   // per-block count slices (no global atomics)

// ---------------- helpers ----------------
__device__ inline float wavesum_f32(float v) {
#pragma unroll
    for (int d = 32; d > 0; d >>= 1) v += __shfl_xor(v, d, 64);
    return v;   // all lanes hold the sum
}
__device__ inline double wavesum_f64(double v) {
#pragma unroll
    for (int d = 32; d > 0; d >>= 1) v += __shfl_down(v, d, 64);
    return v;   // lane 0
}
__device__ inline float exscan64_f32(float v, int lane) {
    float x = v;
#pragma unroll
    for (int d = 1; d < 64; d <<= 1) {
        float y = __shfl_up(x, d, 64);
        if (lane >= d) x += y;
    }
    return x - v;
}
__device__ inline float fast_tanh(float x) {
    // tanh(x) = 1 - 2/(exp(2x)+1); exact limits at +/-inf via exp over/underflow
    float e = __expf(2.f * x);
    return 1.f - 2.f / (e + 1.f);
}

// ---------------- kernels ----------------
__global__ void k_zero() {
    int t = threadIdx.x;
    double* sp = (double*)g_stats;                 // 196 doubles
    for (int i = t; i < NPAIR * 7; i += 256) sp[i] = 0.0;
    if (t < Bn * 2) ((double*)g_cls)[t] = 0.0;
    if (t < Bn) g_seedbg[t] = 0.0;
    if (t < NPAIR) g_seedfg[t] = 0.0;
}

__global__ __launch_bounds__(256) void k_stats(const float* __restrict__ pred,
                                               const int* __restrict__ inst,
                                               const int* __restrict__ lab) {
    int b = blockIdx.y;
    int t = threadIdx.x;
    int lane = t & 63;
    float acc[NID * 7];
#pragma unroll
    for (int i = 0; i < NID * 7; ++i) acc[i] = 0.f;
    float fa = 0.f, va = 0.f, sb = 0.f;

    const float* pb = pred + (size_t)b * Cn * HWn;
    const int*   ib = inst + (size_t)b * HWn;
    const int*   lb = lab  + (size_t)b * HWn;
    int pix0 = blockIdx.x * (256 * PXS) + t;

#pragma unroll
    for (int i = 0; i < PXS; ++i) {
        int pix = pix0 + i * 256;
        int y = pix >> 10;
        int x = pix & 1023;
        float xm = (float)x * (2.0f / 2047.0f);
        float ym = (float)y * (1.0f / 1023.0f);
        int iv = ib[pix];
        int lv = lb[pix];
        float s0 = pb[2 * (size_t)HWn + pix];
        float s1 = pb[3 * (size_t)HWn + pix];
#pragma unroll
        for (int id = 0; id < NID; ++id) {
            float m = (iv == id + 1) ? 1.f : 0.f;
            int a = id * 7;
            acc[a + 0] += m;
            acc[a + 1] += m * xm;
            acc[a + 2] += m * ym;
            acc[a + 3] += m * s0;
            acc[a + 4] += m * s1;
            acc[a + 5] += m * s0 * s0;
            acc[a + 6] += m * s1 * s1;
        }
        if (lv < 2) {
            float c0 = pb[5 * (size_t)HWn + pix];
            float c1 = pb[6 * (size_t)HWn + pix];
            float d  = (lv == 0) ? (c0 - c1) : (c1 - c0);   // binary softmax
            float ed = __expf(-d);
            float pt = 1.f / (1.f + ed);
            float mlogpt = (ed > 1e30f) ? -d : __logf(1.f + ed);  // = -logpt >= 0
            float om = 1.f - pt;
            fa += om * om * mlogpt;
            va += 1.f;
        }
        if (lv == 0) {
            float p4 = pb[4 * (size_t)HWn + pix];
            float seed = 1.f / (1.f + __expf(-p4));
            sb += seed * seed;
        }
    }

    __shared__ float ls[NID * 7 + 3];
    if (t < NID * 7 + 3) ls[t] = 0.f;
    __syncthreads();
#pragma unroll
    for (int i = 0; i < NID * 7; ++i) {
        float v = wavesum_f32(acc[i]);
        if (lane == 0 && v != 0.f) atomicAdd(&ls[i], v);
    }
    {
        float v = wavesum_f32(fa);
        if (lane == 0 && v != 0.f) atomicAdd(&ls[NID * 7 + 0], v);
        v = wavesum_f32(va);
        if (lane == 0 && v != 0.f) atomicAdd(&ls[NID * 7 + 1], v);
        v = wavesum_f32(sb);
        if (lane == 0 && v != 0.f) atomicAdd(&ls[NID * 7 + 2], v);
    }
    __syncthreads();
    if (t < NID * 7) {
        int id = t / 7, s = t % 7;
        if (ls[t] != 0.f) atomicAdd(&g_stats[b * NID + id][s], (double)ls[t]);
    } else if (t == NID * 7 + 0) {
        if (ls[t] != 0.f) atomicAdd(&g_cls[b][0], (double)ls[t]);
    } else if (t == NID * 7 + 1) {
        if (ls[t] != 0.f) atomicAdd(&g_cls[b][1], (double)ls[t]);
    } else if (t == NID * 7 + 2) {
        if (ls[t] != 0.f) atomicAdd(&g_seedbg[b], (double)ls[t]);
    }
}

__global__ __launch_bounds__(256) void k_hist(const float* __restrict__ pred,
                                              const int* __restrict__ inst) {
    int b = blockIdx.y;
    int chunk = blockIdx.x;
    int t = threadIdx.x;
    int lane = t & 63;

    __shared__ unsigned hcnt[SLICE];   // [id][cls][k], count only
    __shared__ float sc[NID][4];       // cx, cy, sx, sy
    __shared__ float lseed[NID];

    for (int i = t; i < SLICE; i += 256) hcnt[i] = 0u;
    if (t < NID) {
        int p = b * NID + t;
        double cnt  = g_stats[p][0];
        double cntf = fmax(cnt, 1.0);
        sc[t][0] = (float)(g_stats[p][1] / cntf);
        sc[t][1] = (float)(g_stats[p][2] / cntf);
        sc[t][2] = expf(10.f * (float)(g_stats[p][3] / cntf));
        sc[t][3] = expf(10.f * (float)(g_stats[p][4] / cntf));
        lseed[t] = 0.f;
    }
    __syncthreads();

    const float* pb = pred + (size_t)b * Cn * HWn;
    const int*   ib = inst + (size_t)b * HWn;
    int pix0 = chunk * (256 * PXH) + t;

    float accs[NID];
#pragma unroll
    for (int i = 0; i < NID; ++i) accs[i] = 0.f;

#pragma unroll 2
    for (int i = 0; i < PXH; ++i) {
        int pix = pix0 + i * 256;
        int y = pix >> 10;
        int x = pix & 1023;
        float xm = (float)x * (2.0f / 2047.0f);
        float ym = (float)y * (1.0f / 1023.0f);
        float p0 = pb[0 * (size_t)HWn + pix];
        float p1 = pb[1 * (size_t)HWn + pix];
        float p4 = pb[4 * (size_t)HWn + pix];
        int   iv = ib[pix];
        float ex = fast_tanh(p0) + xm;
        float ey = fast_tanh(p1) + ym;
        float seed = 1.f / (1.f + __expf(-p4));
#pragma unroll
        for (int id = 0; id < NID; ++id) {
            float dx = ex - sc[id][0];
            float dy = ey - sc[id][1];
            float tt = dx * dx * sc[id][2] + dy * dy * sc[id][3];
            float dist = __expf(-tt);
            bool gt = (iv == id + 1);
            float e = gt ? (2.f - 2.f * dist) : (2.f * dist);
            int k = min(NBK - 1, (int)(e * 128.f));
            atomicAdd(&hcnt[(id * 2 + (gt ? 1 : 0)) * NBK + k], 1u);
            float d2 = seed - dist;
            accs[id] += gt ? d2 * d2 : 0.f;
        }
    }

    // flush histogram slice (plain coalesced stores, no atomics)
    size_t base = ((size_t)b * NCH_H + chunk) * SLICE;
    __syncthreads();
    for (int i = t; i < SLICE; i += 256) g_pcnt[base + i] = hcnt[i];

    // seed_fg reduction: register -> wave -> LDS -> global f64
#pragma unroll
    for (int id = 0; id < NID; ++id) {
        float v = wavesum_f32(accs[id]);
        if (lane == 0 && v != 0.f) atomicAdd(&lseed[id], v);
    }
    __syncthreads();
    if (t < NID && lseed[t] != 0.f)
        atomicAdd(&g_seedfg[b * NID + t], (double)lseed[t]);
}

// grid = 28 pairs, 512 threads: coalesced partial reduction + descending scan
__global__ __launch_bounds__(512) void k_scan() {
    int pair = blockIdx.x;
    int b = pair / NID, id = pair % NID;
    int t = threadIdx.x;

    __shared__ float scnt[2 * NBK];    // [cls][k]

    float cacc = 0.f;
#pragma unroll 4
    for (int c = 0; c < NCH_H; ++c) {
        size_t off = ((size_t)b * NCH_H + c) * SLICE + (size_t)id * (2 * NBK) + t;
        cacc += (float)g_pcnt[off];
    }
    scnt[t] = cacc;
    __syncthreads();

    if (t < 64) {
        int lane = t;
        double G = g_stats[pair][0];
        if (G <= 0.0) {
            if (lane == 0) g_instl[pair] = 0.f;
            return;
        }
        float c0 = 0.f, c1 = 0.f;
#pragma unroll
        for (int jj = 0; jj < 4; ++jj) {
            int k = NBK - 1 - (lane * 4 + jj);
            c0 += scnt[k];
            c1 += scnt[NBK + k];
        }
        float r0  = exscan64_f32(c0, lane);
        float s1b = exscan64_f32(c1, lane);
        double acc = 0.0;
        double r = (double)r0;
        double S = (double)s1b;
#pragma unroll
        for (int jj = 0; jj < 4; ++jj) {
            int k = NBK - 1 - (lane * 4 + jj);
            double cc1 = (double)scnt[NBK + k];
            double cc0 = (double)scnt[k];
            double mid = ((double)k + 0.5) * (1.0 / 128.0);
            double Sin = S + cc1;
            if (cc1 > 0.0) acc += mid * cc1 / (G + r);
            if (cc0 > 0.0) {
                double gr = G + r;
                acc += mid * (G - Sin) * (1.0 / gr - 1.0 / (gr + cc0));
            }
            r += cc0;
            S = Sin;
        }
        acc = wavesum_f64(acc);
        if (lane == 0) g_instl[pair] = (float)acc;
    }
}

__global__ void k_final(float* __restrict__ out) {
    if (blockIdx.x != 0 || threadIdx.x != 0) return;
    double tot = 0.0, totc = 0.0;
    for (int b = 0; b < Bn; ++b) {
        double pres = 0.0, il = 0.0, vl = 0.0, sf = 0.0;
        for (int id = 0; id < NID; ++id) {
            int p = b * NID + id;
            double cnt = g_stats[p][0];
            if (cnt > 0.0) {
                pres += 1.0;
                il += (double)g_instl[p];
                double m0 = g_stats[p][3] / cnt;
                double m1 = g_stats[p][4] / cnt;
                double varsum = (g_stats[p][5] - cnt * m0 * m0) + (g_stats[p][6] - cnt * m1 * m1);
                vl += varsum / (2.0 * cnt);
                sf += 200.0 * g_seedfg[p];
            }
        }
        double obj = fmax(pres, 1.0);
        double seed_loss = (g_seedbg[b] + sf) / (double)HWn;
        tot += il / obj + 10.0 * vl / obj + seed_loss;
        double vc = fmax(g_cls[b][1], 1.0);
        totc += g_cls[b][0] / vc;
    }
    out[0] = (float)(tot / (double)Bn + totc / (double)Bn);
}

// ---------------- launch ----------------
extern "C" void kernel_launch(void* const* d_in, const int* in_sizes, int n_in,
                              void* d_out, int out_size, void* d_ws, size_t ws_size,
                              hipStream_t stream) {
    const float* pred = (const float*)d_in[0];
    const int*   inst = (const int*)d_in[1];
    const int*   lab  = (const int*)d_in[2];
    float* out = (float*)d_out;

    k_zero<<<1, 256, 0, stream>>>();
    k_stats<<<dim3(NCH_S, Bn), 256, 0, stream>>>(pred, inst, lab);
    k_hist<<<dim3(NCH_H, Bn), 256, 0, stream>>>(pred, inst);
    k_scan<<<NPAIR, 512, 0, stream>>>();
    k_final<<<1, 1, 0, stream>>>(out);
}

// Round 5
// 173.267 us; speedup vs baseline: 12.7210x; 1.2403x over previous
//
#include <hip/hip_runtime.h>
#include <math.h>

#define Bn 4
#define Cn 7
#define HWn (512*1024)
#define NID 7
#define NPAIR 28
#define NBK 256               // linear buckets over e in [0,2], width 1/128
#define PXS 8                 // pixels/thread in k_stats
#define NCH_S (HWn/(256*PXS)) // 256
#define PXH 8                 // pixels/thread in k_hist
#define NCH_H (HWn/(256*PXH)) // 256
#define SLICE (NID*2*NBK)     // 3584 u32 per (b,chunk) slice
#define NGRP 8
#define CPG (NCH_H/NGRP)      // 32 chunks per reduce group

// ---------------- static device state ----------------
__device__ double   g_stats[NPAIR][7];   // cnt, Sxm, Sym, Ss0, Ss1, Ss0^2, Ss1^2
__device__ double   g_cls[Bn][2];        // focal_sum, valid_cnt
__device__ double   g_seedbg[Bn];
__device__ double   g_seedfg[NPAIR];
__device__ float    g_instl[NPAIR];
__device__ unsigned g_pcnt[(size_t)Bn*NCH_H*SLICE];   // per-block count slices
__device__ float    g_red[(size_t)NPAIR*NGRP*2*NBK];  // tree-reduced partials

// ---------------- helpers ----------------
__device__ inline float wavesum_f32(float v) {
#pragma unroll
    for (int d = 32; d > 0; d >>= 1) v += __shfl_xor(v, d, 64);
    return v;
}
__device__ inline double wavesum_f64(double v) {
#pragma unroll
    for (int d = 32; d > 0; d >>= 1) v += __shfl_down(v, d, 64);
    return v;   // lane 0
}
__device__ inline float exscan64_f32(float v, int lane) {
    float x = v;
#pragma unroll
    for (int d = 1; d < 64; d <<= 1) {
        float y = __shfl_up(x, d, 64);
        if (lane >= d) x += y;
    }
    return x - v;
}
__device__ inline float fast_tanh(float x) {
    float e = __expf(2.f * x);
    return 1.f - 2.f / (e + 1.f);
}

// ---------------- kernels ----------------
__global__ void k_zero() {
    int t = threadIdx.x;
    double* sp = (double*)g_stats;
    for (int i = t; i < NPAIR * 7; i += 256) sp[i] = 0.0;
    if (t < Bn * 2) ((double*)g_cls)[t] = 0.0;
    if (t < Bn) g_seedbg[t] = 0.0;
    if (t < NPAIR) g_seedfg[t] = 0.0;
}

__device__ inline void stat_px(float xm, float ym, int iv, int lv,
                               float s0, float s1, float c0, float c1, float p4,
                               float* acc, float& fa, float& va, float& sb) {
#pragma unroll
    for (int id = 0; id < NID; ++id) {
        float m = (iv == id + 1) ? 1.f : 0.f;
        int a = id * 7;
        acc[a + 0] += m;
        acc[a + 1] += m * xm;
        acc[a + 2] += m * ym;
        acc[a + 3] += m * s0;
        acc[a + 4] += m * s1;
        acc[a + 5] += m * s0 * s0;
        acc[a + 6] += m * s1 * s1;
    }
    if (lv < 2) {
        float d  = (lv == 0) ? (c0 - c1) : (c1 - c0);
        float ed = __expf(-d);
        float pt = 1.f / (1.f + ed);
        float mlogpt = (ed > 1e30f) ? -d : __logf(1.f + ed);
        float om = 1.f - pt;
        fa += om * om * mlogpt;
        va += 1.f;
    }
    if (lv == 0) {
        float seed = 1.f / (1.f + __expf(-p4));
        sb += seed * seed;
    }
}

__global__ __launch_bounds__(256, 4) void k_stats(const float* __restrict__ pred,
                                                  const int* __restrict__ inst,
                                                  const int* __restrict__ lab) {
    int b = blockIdx.y;
    int t = threadIdx.x;
    int lane = t & 63;
    float acc[NID * 7];
#pragma unroll
    for (int i = 0; i < NID * 7; ++i) acc[i] = 0.f;
    float fa = 0.f, va = 0.f, sb = 0.f;

    const float* pb = pred + (size_t)b * Cn * HWn;
    const int*   ib = inst + (size_t)b * HWn;
    const int*   lb = lab  + (size_t)b * HWn;
    int cb = blockIdx.x * (256 * PXS);   // 2048-px chunk

#pragma unroll
    for (int j = 0; j < PXS / 4; ++j) {
        int px0 = cb + j * 1024 + (t << 2);       // 4 consecutive px, same row
        int y = px0 >> 10;
        int x = px0 & 1023;
        float xmb = (float)x * (2.0f / 2047.0f);
        float ym  = (float)y * (1.0f / 1023.0f);
        const float DX = 2.0f / 2047.0f;
        int4   iv4 = *(const int4*)(ib + px0);
        int4   lv4 = *(const int4*)(lb + px0);
        float4 s0v = *(const float4*)(pb + 2 * (size_t)HWn + px0);
        float4 s1v = *(const float4*)(pb + 3 * (size_t)HWn + px0);
        float4 p4v = *(const float4*)(pb + 4 * (size_t)HWn + px0);
        float4 c0v = *(const float4*)(pb + 5 * (size_t)HWn + px0);
        float4 c1v = *(const float4*)(pb + 6 * (size_t)HWn + px0);
        stat_px(xmb + 0*DX, ym, iv4.x, lv4.x, s0v.x, s1v.x, c0v.x, c1v.x, p4v.x, acc, fa, va, sb);
        stat_px(xmb + 1*DX, ym, iv4.y, lv4.y, s0v.y, s1v.y, c0v.y, c1v.y, p4v.y, acc, fa, va, sb);
        stat_px(xmb + 2*DX, ym, iv4.z, lv4.z, s0v.z, s1v.z, c0v.z, c1v.z, p4v.z, acc, fa, va, sb);
        stat_px(xmb + 3*DX, ym, iv4.w, lv4.w, s0v.w, s1v.w, c0v.w, c1v.w, p4v.w, acc, fa, va, sb);
    }

    __shared__ float ls[NID * 7 + 3];
    if (t < NID * 7 + 3) ls[t] = 0.f;
    __syncthreads();
#pragma unroll
    for (int i = 0; i < NID * 7; ++i) {
        float v = wavesum_f32(acc[i]);
        if (lane == 0 && v != 0.f) atomicAdd(&ls[i], v);
    }
    {
        float v = wavesum_f32(fa);
        if (lane == 0 && v != 0.f) atomicAdd(&ls[NID * 7 + 0], v);
        v = wavesum_f32(va);
        if (lane == 0 && v != 0.f) atomicAdd(&ls[NID * 7 + 1], v);
        v = wavesum_f32(sb);
        if (lane == 0 && v != 0.f) atomicAdd(&ls[NID * 7 + 2], v);
    }
    __syncthreads();
    if (t < NID * 7) {
        int id = t / 7, s = t % 7;
        if (ls[t] != 0.f) atomicAdd(&g_stats[b * NID + id][s], (double)ls[t]);
    } else if (t == NID * 7 + 0) {
        if (ls[t] != 0.f) atomicAdd(&g_cls[b][0], (double)ls[t]);
    } else if (t == NID * 7 + 1) {
        if (ls[t] != 0.f) atomicAdd(&g_cls[b][1], (double)ls[t]);
    } else if (t == NID * 7 + 2) {
        if (ls[t] != 0.f) atomicAdd(&g_seedbg[b], (double)ls[t]);
    }
}

__device__ inline void hist_px(float xm, float ym, float p0, float p1, float p4, int iv,
                               const float4* scr, float* accs, unsigned* hcnt) {
    float ex = fast_tanh(p0) + xm;
    float ey = fast_tanh(p1) + ym;
    float seed = 1.f / (1.f + __expf(-p4));
#pragma unroll
    for (int id = 0; id < NID; ++id) {
        float dx = ex - scr[id].x;
        float dy = ey - scr[id].y;
        float tt = dx * dx * scr[id].z + dy * dy * scr[id].w;
        float dist = __expf(-tt);
        bool gt = (iv == id + 1);
        float e = gt ? (2.f - 2.f * dist) : (2.f * dist);
        int k = min(NBK - 1, (int)(e * 128.f));
        atomicAdd(&hcnt[(id * 2 + (gt ? 1 : 0)) * NBK + k], 1u);
        float d2 = seed - dist;
        accs[id] += gt ? d2 * d2 : 0.f;
    }
}

__global__ __launch_bounds__(256, 4) void k_hist(const float* __restrict__ pred,
                                                 const int* __restrict__ inst) {
    int b = blockIdx.y;
    int chunk = blockIdx.x;
    int t = threadIdx.x;
    int lane = t & 63;

    __shared__ unsigned hcnt[SLICE];
    __shared__ float4 scs[NID];
    __shared__ float lseed[NID];

    for (int i = t; i < SLICE; i += 256) hcnt[i] = 0u;
    if (t < NID) {
        int p = b * NID + t;
        double cnt  = g_stats[p][0];
        double cntf = fmax(cnt, 1.0);
        scs[t] = make_float4((float)(g_stats[p][1] / cntf),
                             (float)(g_stats[p][2] / cntf),
                             expf(10.f * (float)(g_stats[p][3] / cntf)),
                             expf(10.f * (float)(g_stats[p][4] / cntf)));
        lseed[t] = 0.f;
    }
    __syncthreads();

    float4 scr[NID];
#pragma unroll
    for (int id = 0; id < NID; ++id) scr[id] = scs[id];

    const float* pb = pred + (size_t)b * Cn * HWn;
    const int*   ib = inst + (size_t)b * HWn;
    int cb = chunk * (256 * PXH);

    float accs[NID];
#pragma unroll
    for (int i = 0; i < NID; ++i) accs[i] = 0.f;

#pragma unroll
    for (int j = 0; j < PXH / 4; ++j) {
        int px0 = cb + j * 1024 + (t << 2);
        int y = px0 >> 10;
        int x = px0 & 1023;
        float xmb = (float)x * (2.0f / 2047.0f);
        float ym  = (float)y * (1.0f / 1023.0f);
        const float DX = 2.0f / 2047.0f;
        float4 p0v = *(const float4*)(pb + 0 * (size_t)HWn + px0);
        float4 p1v = *(const float4*)(pb + 1 * (size_t)HWn + px0);
        float4 p4v = *(const float4*)(pb + 4 * (size_t)HWn + px0);
        int4   iv4 = *(const int4*)(ib + px0);
        hist_px(xmb + 0*DX, ym, p0v.x, p1v.x, p4v.x, iv4.x, scr, accs, hcnt);
        hist_px(xmb + 1*DX, ym, p0v.y, p1v.y, p4v.y, iv4.y, scr, accs, hcnt);
        hist_px(xmb + 2*DX, ym, p0v.z, p1v.z, p4v.z, iv4.z, scr, accs, hcnt);
        hist_px(xmb + 3*DX, ym, p0v.w, p1v.w, p4v.w, iv4.w, scr, accs, hcnt);
    }

    // flush histogram slice (plain coalesced stores)
    size_t base = ((size_t)b * NCH_H + chunk) * SLICE;
    __syncthreads();
    for (int i = t; i < SLICE; i += 256) g_pcnt[base + i] = hcnt[i];

    // seed_fg: register -> wave -> LDS -> global f64
#pragma unroll
    for (int id = 0; id < NID; ++id) {
        float v = wavesum_f32(accs[id]);
        if (lane == 0 && v != 0.f) atomicAdd(&lseed[id], v);
    }
    __syncthreads();
    if (t < NID && lseed[t] != 0.f)
        atomicAdd(&g_seedfg[b * NID + t], (double)lseed[t]);
}

// tree stage: 28 pairs x 8 groups, each block sums 32 chunks of its 512-entry sub-slice
__global__ __launch_bounds__(512) void k_reduce() {
    int pg = blockIdx.x;
    int pair = pg / NGRP, g = pg % NGRP;
    int b = pair / NID, id = pair % NID;
    int t = threadIdx.x;   // 0..511 = cls*NBK + k
    float acc = 0.f;
#pragma unroll 4
    for (int c = 0; c < CPG; ++c) {
        int chunk = g * CPG + c;
        size_t off = ((size_t)(b * NCH_H + chunk)) * SLICE + (size_t)id * (2 * NBK) + t;
        acc += (float)g_pcnt[off];
    }
    g_red[(size_t)pg * (2 * NBK) + t] = acc;
}

// 28 blocks x 512 threads: final sum + descending closed-form scan
__global__ __launch_bounds__(512) void k_scan() {
    int pair = blockIdx.x;
    int t = threadIdx.x;

    __shared__ float scnt[2 * NBK];

    float cacc = 0.f;
#pragma unroll
    for (int g = 0; g < NGRP; ++g)
        cacc += g_red[(size_t)(pair * NGRP + g) * (2 * NBK) + t];
    scnt[t] = cacc;
    __syncthreads();

    if (t < 64) {
        int lane = t;
        double G = g_stats[pair][0];
        if (G <= 0.0) {
            if (lane == 0) g_instl[pair] = 0.f;
            return;
        }
        float c0 = 0.f, c1 = 0.f;
#pragma unroll
        for (int jj = 0; jj < 4; ++jj) {
            int k = NBK - 1 - (lane * 4 + jj);
            c0 += scnt[k];
            c1 += scnt[NBK + k];
        }
        float r0  = exscan64_f32(c0, lane);
        float s1b = exscan64_f32(c1, lane);
        double acc = 0.0;
        double r = (double)r0;
        double S = (double)s1b;
#pragma unroll
        for (int jj = 0; jj < 4; ++jj) {
            int k = NBK - 1 - (lane * 4 + jj);
            double cc1 = (double)scnt[NBK + k];
            double cc0 = (double)scnt[k];
            double mid = ((double)k + 0.5) * (1.0 / 128.0);
            double Sin = S + cc1;
            if (cc1 > 0.0) acc += mid * cc1 / (G + r);
            if (cc0 > 0.0) {
                double gr = G + r;
                acc += mid * (G - Sin) * (1.0 / gr - 1.0 / (gr + cc0));
            }
            r += cc0;
            S = Sin;
        }
        acc = wavesum_f64(acc);
        if (lane == 0) g_instl[pair] = (float)acc;
    }
}

__global__ void k_final(float* __restrict__ out) {
    if (blockIdx.x != 0 || threadIdx.x != 0) return;
    double tot = 0.0, totc = 0.0;
    for (int b = 0; b < Bn; ++b) {
        double pres = 0.0, il = 0.0, vl = 0.0, sf = 0.0;
        for (int id = 0; id < NID; ++id) {
            int p = b * NID + id;
            double cnt = g_stats[p][0];
            if (cnt > 0.0) {
                pres += 1.0;
                il += (double)g_instl[p];
                double m0 = g_stats[p][3] / cnt;
                double m1 = g_stats[p][4] / cnt;
                double varsum = (g_stats[p][5] - cnt * m0 * m0) + (g_stats[p][6] - cnt * m1 * m1);
                vl += varsum / (2.0 * cnt);
                sf += 200.0 * g_seedfg[p];
            }
        }
        double obj = fmax(pres, 1.0);
        double seed_loss = (g_seedbg[b] + sf) / (double)HWn;
        tot += il / obj + 10.0 * vl / obj + seed_loss;
        double vc = fmax(g_cls[b][1], 1.0);
        totc += g_cls[b][0] / vc;
    }
    out[0] = (float)(tot / (double)Bn + totc / (double)Bn);
}

// ---------------- launch ----------------
extern "C" void kernel_launch(void* const* d_in, const int* in_sizes, int n_in,
                              void* d_out, int out_size, void* d_ws, size_t ws_size,
                              hipStream_t stream) {
    const float* pred = (const float*)d_in[0];
    const int*   inst = (const int*)d_in[1];
    const int*   lab  = (const int*)d_in[2];
    float* out = (float*)d_out;

    k_zero<<<1, 256, 0, stream>>>();
    k_stats<<<dim3(NCH_S, Bn), 256, 0, stream>>>(pred, inst, lab);
    k_hist<<<dim3(NCH_H, Bn), 256, 0, stream>>>(pred, inst);
    k_reduce<<<NPAIR * NGRP, 512, 0, stream>>>();
    k_scan<<<NPAIR, 512, 0, stream>>>();
    k_final<<<1, 1, 0, stream>>>(out);
}